// Round 16
// baseline (221.653 us; speedup 1.0000x reference)
//
#include <hip/hip_runtime.h>
#include <hip/hip_bf16.h>
#include <stdint.h>

#define SEQ 2048
#define BATCH 2
#define NTOK (SEQ * BATCH)   // 4096
#define HID 2048
#define NQH 16
#define NKVH 4
#define HD 128
#define KVD 512              // NKVH * HD

typedef __bf16 bf16x8 __attribute__((ext_vector_type(8)));
typedef float f32x4 __attribute__((ext_vector_type(4)));
typedef float f32x16 __attribute__((ext_vector_type(16)));
typedef unsigned int u32;

__device__ __forceinline__ unsigned short f2bf(float f) {
    uint32_t u = __builtin_bit_cast(uint32_t, f);
    uint32_t r = (u + 0x7fffu + ((u >> 16) & 1u)) >> 16;
    return (unsigned short)r;
}

__device__ __forceinline__ u32 cvtpk(float lo, float hi) {
    u32 r;
    asm("v_cvt_pk_bf16_f32 %0, %1, %2" : "=v"(r) : "v"(lo), "v"(hi));
    return r;
}

// async global->LDS, 16B per lane. lds ptr must be wave-uniform (HW appends lane*16).
__device__ __forceinline__ void gload16(const void* g, void* l) {
    __builtin_amdgcn_global_load_lds((const __attribute__((address_space(1))) u32*)g,
                                     (__attribute__((address_space(3))) u32*)l, 16, 0, 0);
}

#define BARRIER()  asm volatile("s_barrier" ::: "memory")
#define VMCNT(n)   asm volatile("s_waitcnt vmcnt(" #n ")" ::: "memory")

// ---------------- fp32 -> bf16 convert (vectorized) ----------------
__global__ void cvt_f32_bf16(const float* __restrict__ in, unsigned short* __restrict__ out, int n4) {
    int i = blockIdx.x * blockDim.x + threadIdx.x;
    int stride = gridDim.x * blockDim.x;
    for (; i < n4; i += stride) {
        float4 v = ((const float4*)in)[i];
        ushort4 o;
        o.x = f2bf(v.x); o.y = f2bf(v.y); o.z = f2bf(v.z); o.w = f2bf(v.w);
        ((ushort4*)out)[i] = o;
    }
}

// ------------- all W [2048][N] fp32 -> Wt [N][2048] bf16, one launch --------------
__global__ __launch_bounds__(256) void transpose_all(const float* __restrict__ Wq,
                                                     const float* __restrict__ Wk,
                                                     const float* __restrict__ Wv,
                                                     const float* __restrict__ Wo,
                                                     unsigned short* __restrict__ Wqkvt,
                                                     unsigned short* __restrict__ Wot) {
    __shared__ unsigned short tile[64][72];
    const int y = blockIdx.y;
    const float* W;
    unsigned short* dst;
    int N, ny;
    if (y < 32)      { W = Wq; dst = Wqkvt;                        N = 2048; ny = y; }
    else if (y < 40) { W = Wk; dst = Wqkvt + (size_t)2048 * HID;   N = 512;  ny = y - 32; }
    else if (y < 48) { W = Wv; dst = Wqkvt + (size_t)2560 * HID;   N = 512;  ny = y - 40; }
    else             { W = Wo; dst = Wot;                          N = 2048; ny = y - 48; }
    const int k0 = blockIdx.x * 64, n0 = ny * 64;
    const int t = threadIdx.x;
    const int r = t >> 4;          // 0..15
    const int c4 = (t & 15) * 4;   // 0..60
    #pragma unroll
    for (int i = 0; i < 4; i++) {
        int row = r + i * 16;
        float4 v = *(const float4*)&W[(size_t)(k0 + row) * N + n0 + c4];
        tile[row][c4 + 0] = f2bf(v.x);
        tile[row][c4 + 1] = f2bf(v.y);
        tile[row][c4 + 2] = f2bf(v.z);
        tile[row][c4 + 3] = f2bf(v.w);
    }
    __syncthreads();
    #pragma unroll
    for (int i = 0; i < 4; i++) {
        int nrow = r + i * 16;
        ushort4 o;
        o.x = tile[c4 + 0][nrow];
        o.y = tile[c4 + 1][nrow];
        o.z = tile[c4 + 2][nrow];
        o.w = tile[c4 + 3][nrow];
        *(ushort4*)&dst[(size_t)(n0 + nrow) * HID + k0 + c4] = o;
    }
}

// ==== 128^2-tile, BK=64, DOUBLE-buffered + counted vmcnt (64 KB LDS, 2 blocks/CU) ====
// 32 K-steps (half of BK=32), 32 MFMA/wave/step. Wait vmcnt(8) targets the tile issued
// one full step earlier -> latency hidden; 8 loads of the next tile stay in flight.
// MODE 0: fused QKV  C[4096,3072]: nb<16 Q (scaled by 1/sqrt(128)*log2e), nb<20 K, else V^T
// MODE 1: O-proj     C[4096,2048] fp32
template <int MODE>
__global__ __launch_bounds__(256) void gemm128(const unsigned short* __restrict__ A,
                                               const unsigned short* __restrict__ Bt,
                                               const float* __restrict__ b0,
                                               const float* __restrict__ b1,
                                               const float* __restrict__ b2,
                                               void* __restrict__ o0,
                                               void* __restrict__ o1,
                                               void* __restrict__ o2) {
    __shared__ __align__(16) unsigned short Asm[2][128 * 64];   // 16 KB per buf
    __shared__ __align__(16) unsigned short Bsm[2][128 * 64];
    const int NK = HID / 64;                     // 32 K-steps
    const int m0 = blockIdx.x * 128;
    const int nb = blockIdx.y;
    const int n0 = nb * 128;
    const int t = threadIdx.x;
    const int lane = t & 63, w = t >> 6;
    const int wr = (w >> 1) * 64, wc = (w & 1) * 64;
    const int l16 = lane & 15, lg = lane >> 4;

    f32x4 acc[4][4] = {};

    // stage tile kt (A+B, 16 KB each) into buf: 4+4 gloads/thread (8 vm-instr)
    auto stage = [&](int buf, int kt) {
        const int k0 = kt * 64;
        #pragma unroll
        for (int it = 0; it < 4; it++) {
            int base = it * 256 + w * 64;          // wave-uniform chunk base
            int qc = base + lane;                  // chunk 0..1023 (row*8 + c)
            int row = qc >> 3, c = qc & 7;
            int col = ((c ^ (row & 7)) << 3);      // pre-swizzled source col
            gload16(&A[(size_t)(m0 + row) * HID + k0 + col], (char*)&Asm[buf][0] + base * 16);
            gload16(&Bt[(size_t)(n0 + row) * HID + k0 + col], (char*)&Bsm[buf][0] + base * 16);
        }
    };

    stage(0, 0);
    int buf = 0;
    for (int kt = 0; kt < NK; kt++) {
        if (kt + 1 < NK) { stage(buf ^ 1, kt + 1); VMCNT(8); }
        else             { VMCNT(0); }
        BARRIER();
        const char* Ab = (const char*)&Asm[buf][0];
        const char* Bb = (const char*)&Bsm[buf][0];
        #pragma unroll
        for (int kk = 0; kk < 2; kk++) {
            bf16x8 af[4], bfr[4];
            #pragma unroll
            for (int m = 0; m < 4; m++) {
                int row = wr + m * 16 + l16;
                af[m] = *(const bf16x8*)(Ab + row * 128 + (((kk * 4 + lg) ^ (row & 7)) << 4));
            }
            #pragma unroll
            for (int n = 0; n < 4; n++) {
                int row = wc + n * 16 + l16;
                bfr[n] = *(const bf16x8*)(Bb + row * 128 + (((kk * 4 + lg) ^ (row & 7)) << 4));
            }
            #pragma unroll
            for (int m = 0; m < 4; m++)
                #pragma unroll
                for (int n = 0; n < 4; n++)
                    acc[m][n] = __builtin_amdgcn_mfma_f32_16x16x32_bf16(af[m], bfr[n], acc[m][n], 0, 0, 0);
        }
        BARRIER();                               // reads retired before buf reuse
        buf ^= 1;
    }

    // epilogue
    const float sc = 0.12751744954313278f;   // 1/sqrt(128) * log2(e) — attn uses exp2
    #pragma unroll
    for (int m = 0; m < 4; m++) {
        int row = m0 + wr + m * 16 + lg * 4;
        #pragma unroll
        for (int n = 0; n < 4; n++) {
            int col = n0 + wc + n * 16 + l16;
            #pragma unroll
            for (int r = 0; r < 4; r++) {
                float v = acc[m][n][r];
                int rr = row + r;
                if constexpr (MODE == 0) {
                    if (nb < 16) {
                        v = (v + b0[col]) * sc;
                        ((unsigned short*)o0)[(size_t)rr * HID + col] = f2bf(v);
                    } else if (nb < 20) {
                        int c = col - 2048;
                        v += b1[c];
                        ((unsigned short*)o1)[(size_t)rr * KVD + c] = f2bf(v);
                    } else {
                        int c = col - 2560;
                        v += b2[c];
                        int b = rr >> 11, s = rr & (SEQ - 1);
                        ((unsigned short*)o2)[((size_t)b * KVD + c) * SEQ + s] = f2bf(v);
                    }
                } else {
                    v += b0[col];
                    ((float*)o0)[(size_t)rr * HID + col] = v;
                }
            }
        }
    }
}

// ---------------- causal GQA flash attention (r12-best: dbuf + exp2 + tree-max) ----------------
__global__ __launch_bounds__(256, 2) void attn(const unsigned short* __restrict__ Q,
                                               const unsigned short* __restrict__ K,
                                               const unsigned short* __restrict__ Vt,
                                               unsigned short* __restrict__ ctx) {
    __shared__ unsigned short Ksm[2][64 * 128];
    __shared__ unsigned short Vsm[2][128 * 64];
    const int n = blockIdx.x;                     // 0..511
    const int qt = 15 - (n >> 5);                 // LPT: heaviest q-tiles first
    const int bh = n & 31;
    const int b = bh >> 4, h = bh & 15, hk = h >> 2;
    const int t = threadIdx.x, w = t >> 6, lane = t & 63;
    const int lam = lane & 31, hi = lane >> 5;
    const int qw = qt * 128 + w * 32;
    const int qg = qw + lam;
    const size_t qrowbase = (size_t)b * SEQ + qw;

    const unsigned short* Kg = K + (size_t)b * SEQ * KVD + hk * HD;
    const unsigned short* Vg = Vt + ((size_t)b * KVD + hk * HD) * SEQ;

    bf16x8 qf[8];
    #pragma unroll
    for (int kc = 0; kc < 8; kc++)
        qf[kc] = *(const bf16x8*)&Q[(qrowbase + lam) * HID + h * HD + kc * 16 + hi * 8];

    f32x16 oacc[4] = {};
    float m = -1e30f, l = 0.f;

    auto stage = [&](int buf, int kt) {
        const int kvb = kt * 64;
        #pragma unroll
        for (int it = 0; it < 4; it++) {
            int base = it * 256 + w * 64;
            int qc = base + lane;
            {   // K tile: 64 rows x 16 slots of 16B
                int row = qc >> 4, c = qc & 15;
                gload16(&Kg[(size_t)(kvb + row) * KVD + ((c ^ (row & 7)) << 3)],
                        (char*)&Ksm[buf][0] + base * 16);
            }
            {   // V^T tile: 128 rows x 8 slots
                int row = qc >> 3, c = qc & 7;
                gload16(&Vg[(size_t)row * SEQ + kvb + ((c ^ (row & 7)) << 3)],
                        (char*)&Vsm[buf][0] + base * 16);
            }
        }
    };

    const int ntile = 2 * qt + 2;
    stage(0, 0);
    __syncthreads();
    int buf = 0;
    for (int kt = 0; kt < ntile; kt++) {
        const int kvb = kt * 64;
        if (kt + 1 < ntile) stage(buf ^ 1, kt + 1);
        if (kvb <= qw + 31) {
            const char* Kb = (const char*)&Ksm[buf][0];
            const char* Vb = (const char*)&Vsm[buf][0];
            f32x16 st0 = {}, st1 = {};
            #pragma unroll
            for (int kc = 0; kc < 8; kc++) {
                int coff = (kc * 32 + hi * 16) ^ ((lam & 7) << 4);
                bf16x8 kf0 = *(const bf16x8*)(Kb + lam * 256 + coff);
                bf16x8 kf1 = *(const bf16x8*)(Kb + (32 + lam) * 256 + coff);
                st0 = __builtin_amdgcn_mfma_f32_32x32x16_bf16(kf0, qf[kc], st0, 0, 0, 0);
                st1 = __builtin_amdgcn_mfma_f32_32x32x16_bf16(kf1, qf[kc], st1, 0, 0, 0);
            }
            if (kvb + 63 > qw) {
                #pragma unroll
                for (int r = 0; r < 16; r++) {
                    int krow = (r & 3) + 8 * (r >> 2) + 4 * hi;
                    if (kvb + krow > qg) st0[r] = -1e30f;
                    if (kvb + 32 + krow > qg) st1[r] = -1e30f;
                }
            }
            // tree max
            float mx[8];
            #pragma unroll
            for (int r = 0; r < 8; r++) mx[r] = fmaxf(st0[r], st0[r + 8]);
            #pragma unroll
            for (int r = 0; r < 8; r++) mx[r] = fmaxf(mx[r], fmaxf(st1[r], st1[r + 8]));
            #pragma unroll
            for (int r = 0; r < 4; r++) mx[r] = fmaxf(mx[r], mx[r + 4]);
            float tmax = fmaxf(fmaxf(mx[0], mx[1]), fmaxf(mx[2], mx[3]));
            tmax = fmaxf(tmax, __shfl_xor(tmax, 32));
            float mn = fmaxf(m, tmax);
            float sf = __builtin_amdgcn_exp2f(m - mn);
            m = mn;
            float rs = 0.f;
            #pragma unroll
            for (int r = 0; r < 16; r++) { st0[r] = __builtin_amdgcn_exp2f(st0[r] - mn); rs += st0[r]; }
            #pragma unroll
            for (int r = 0; r < 16; r++) { st1[r] = __builtin_amdgcn_exp2f(st1[r] - mn); rs += st1[r]; }
            rs += __shfl_xor(rs, 32);
            l = l * sf + rs;
            #pragma unroll
            for (int dc = 0; dc < 4; dc++)
                #pragma unroll
                for (int r = 0; r < 16; r++) oacc[dc][r] *= sf;
            u32 pw0[4][2], pw1[4][2];
            #pragma unroll
            for (int g = 0; g < 4; g++) {
                pw0[g][0] = cvtpk(st0[4 * g], st0[4 * g + 1]);
                pw0[g][1] = cvtpk(st0[4 * g + 2], st0[4 * g + 3]);
                pw1[g][0] = cvtpk(st1[4 * g], st1[4 * g + 1]);
                pw1[g][1] = cvtpk(st1[4 * g + 2], st1[4 * g + 3]);
            }
            #pragma unroll
            for (int kc = 0; kc < 4; kc++) {
                const u32 (*pw)[2] = (kc >> 1) ? pw1 : pw0;
                int g0 = (kc & 1) * 2;
                u32 own0 = hi ? pw[g0 + 1][0] : pw[g0][0];
                u32 own1 = hi ? pw[g0 + 1][1] : pw[g0][1];
                u32 off0 = hi ? pw[g0][0] : pw[g0 + 1][0];
                u32 off1 = hi ? pw[g0][1] : pw[g0 + 1][1];
                u32 xw0 = __shfl_xor(off0, 32);
                u32 xw1 = __shfl_xor(off1, 32);
                int4 paw;
                paw.x = hi ? xw0 : own0;
                paw.y = hi ? xw1 : own1;
                paw.z = hi ? own0 : xw0;
                paw.w = hi ? own1 : xw1;
                bf16x8 pa = __builtin_bit_cast(bf16x8, paw);
                #pragma unroll
                for (int dc = 0; dc < 4; dc++) {
                    bf16x8 vf = *(const bf16x8*)(Vb + (dc * 32 + lam) * 128 +
                                                 ((kc * 32 + hi * 16) ^ ((lam & 7) << 4)));
                    oacc[dc] = __builtin_amdgcn_mfma_f32_32x32x16_bf16(vf, pa, oacc[dc], 0, 0, 0);
                }
            }
        }
        __syncthreads();
        buf ^= 1;
    }

    float inv = 1.f / l;
    char* osm = (char*)&Ksm[0][0] + w * 8192;
    #pragma unroll
    for (int dc = 0; dc < 4; dc++)
        #pragma unroll
        for (int r = 0; r < 16; r += 2) {
            int d = dc * 32 + (r & 3) + 8 * (r >> 2) + 4 * hi;
            u32 wd = cvtpk(oacc[dc][r] * inv, oacc[dc][r + 1] * inv);
            *(u32*)(osm + lam * 256 + ((d * 2) ^ ((lam & 7) << 4))) = wd;
        }
    __syncthreads();
    const int q2 = lane >> 1, half = lane & 1;
    #pragma unroll
    for (int cc = 0; cc < 8; cc++) {
        bf16x8 v = *(const bf16x8*)(osm + q2 * 256 + (((half * 8 + cc) * 16) ^ ((q2 & 7) << 4)));
        *(bf16x8*)&ctx[(qrowbase + q2) * HID + h * HD + half * 64 + cc * 8] = v;
    }
}

extern "C" void kernel_launch(void* const* d_in, const int* in_sizes, int n_in,
                              void* d_out, int out_size, void* d_ws, size_t ws_size,
                              hipStream_t stream) {
    const float* X  = (const float*)d_in[0];
    const float* Wq = (const float*)d_in[1];
    const float* bq = (const float*)d_in[2];
    const float* Wk = (const float*)d_in[3];
    const float* bk = (const float*)d_in[4];
    const float* Wv = (const float*)d_in[5];
    const float* bv = (const float*)d_in[6];
    const float* Wo = (const float*)d_in[7];
    const float* bo = (const float*)d_in[8];
    float* out = (float*)d_out;

    const size_t MB = 1u << 20;
    char* ws = (char*)d_ws;
    if (ws_size < 76 * MB) return;
    unsigned short* Xb    = (unsigned short*)(ws + 0 * MB);    // [4096][2048] bf16
    unsigned short* Wqkvt = (unsigned short*)(ws + 16 * MB);   // [3072][2048]
    unsigned short* Wot   = (unsigned short*)(ws + 28 * MB);   // [2048][2048]
    unsigned short* Qb    = (unsigned short*)(ws + 36 * MB);   // [4096][2048]
    unsigned short* Kb    = (unsigned short*)(ws + 52 * MB);   // [4096][512]
    unsigned short* Vtb   = (unsigned short*)(ws + 56 * MB);   // [2][512][2048]
    unsigned short* Ctx   = (unsigned short*)(ws + 60 * MB);   // [4096][2048]

    cvt_f32_bf16<<<2048, 256, 0, stream>>>(X, Xb, NTOK * HID / 4);
    transpose_all<<<dim3(32, 80), 256, 0, stream>>>(Wq, Wk, Wv, Wo, Wqkvt, Wot);

    gemm128<0><<<dim3(32, 24), 256, 0, stream>>>(Xb, Wqkvt, bq, bk, bv, Qb, Kb, Vtb);

    attn<<<dim3(512), 256, 0, stream>>>(Qb, Kb, Vtb, Ctx);

    gemm128<1><<<dim3(32, 16), 256, 0, stream>>>(Ctx, Wot, bo, nullptr, nullptr, (void*)out, nullptr, nullptr);
}

// Round 17
// 206.461 us; speedup vs baseline: 1.0736x; 1.0736x over previous
//
#include <hip/hip_runtime.h>
#include <hip/hip_bf16.h>
#include <stdint.h>

#define SEQ 2048
#define BATCH 2
#define NTOK (SEQ * BATCH)   // 4096
#define HID 2048
#define NQH 16
#define NKVH 4
#define HD 128
#define KVD 512              // NKVH * HD

typedef __bf16 bf16x8 __attribute__((ext_vector_type(8)));
typedef float f32x4 __attribute__((ext_vector_type(4)));
typedef float f32x16 __attribute__((ext_vector_type(16)));
typedef unsigned int u32;

__device__ __forceinline__ unsigned short f2bf(float f) {
    uint32_t u = __builtin_bit_cast(uint32_t, f);
    uint32_t r = (u + 0x7fffu + ((u >> 16) & 1u)) >> 16;
    return (unsigned short)r;
}

__device__ __forceinline__ u32 cvtpk(float lo, float hi) {
    u32 r;
    asm("v_cvt_pk_bf16_f32 %0, %1, %2" : "=v"(r) : "v"(lo), "v"(hi));
    return r;
}

// async global->LDS, 16B per lane. lds ptr must be wave-uniform (HW appends lane*16).
__device__ __forceinline__ void gload16(const void* g, void* l) {
    __builtin_amdgcn_global_load_lds((const __attribute__((address_space(1))) u32*)g,
                                     (__attribute__((address_space(3))) u32*)l, 16, 0, 0);
}

#define BARRIER()  asm volatile("s_barrier" ::: "memory")
#define VMCNT(n)   asm volatile("s_waitcnt vmcnt(" #n ")" ::: "memory")

// ---------------- fp32 -> bf16 convert (vectorized) ----------------
__global__ void cvt_f32_bf16(const float* __restrict__ in, unsigned short* __restrict__ out, int n4) {
    int i = blockIdx.x * blockDim.x + threadIdx.x;
    int stride = gridDim.x * blockDim.x;
    for (; i < n4; i += stride) {
        float4 v = ((const float4*)in)[i];
        ushort4 o;
        o.x = f2bf(v.x); o.y = f2bf(v.y); o.z = f2bf(v.z); o.w = f2bf(v.w);
        ((ushort4*)out)[i] = o;
    }
}

// ------------- all W [2048][N] fp32 -> Wt [N][2048] bf16, one launch --------------
__global__ __launch_bounds__(256) void transpose_all(const float* __restrict__ Wq,
                                                     const float* __restrict__ Wk,
                                                     const float* __restrict__ Wv,
                                                     const float* __restrict__ Wo,
                                                     unsigned short* __restrict__ Wqkvt,
                                                     unsigned short* __restrict__ Wot) {
    __shared__ unsigned short tile[64][72];
    const int y = blockIdx.y;
    const float* W;
    unsigned short* dst;
    int N, ny;
    if (y < 32)      { W = Wq; dst = Wqkvt;                        N = 2048; ny = y; }
    else if (y < 40) { W = Wk; dst = Wqkvt + (size_t)2048 * HID;   N = 512;  ny = y - 32; }
    else if (y < 48) { W = Wv; dst = Wqkvt + (size_t)2560 * HID;   N = 512;  ny = y - 40; }
    else             { W = Wo; dst = Wot;                          N = 2048; ny = y - 48; }
    const int k0 = blockIdx.x * 64, n0 = ny * 64;
    const int t = threadIdx.x;
    const int r = t >> 4;          // 0..15
    const int c4 = (t & 15) * 4;   // 0..60
    #pragma unroll
    for (int i = 0; i < 4; i++) {
        int row = r + i * 16;
        float4 v = *(const float4*)&W[(size_t)(k0 + row) * N + n0 + c4];
        tile[row][c4 + 0] = f2bf(v.x);
        tile[row][c4 + 1] = f2bf(v.y);
        tile[row][c4 + 2] = f2bf(v.z);
        tile[row][c4 + 3] = f2bf(v.w);
    }
    __syncthreads();
    #pragma unroll
    for (int i = 0; i < 4; i++) {
        int nrow = r + i * 16;
        ushort4 o;
        o.x = tile[c4 + 0][nrow];
        o.y = tile[c4 + 1][nrow];
        o.z = tile[c4 + 2][nrow];
        o.w = tile[c4 + 3][nrow];
        *(ushort4*)&dst[(size_t)(n0 + nrow) * HID + k0 + c4] = o;
    }
}

// ==== 128^2-tile, BK=32, DOUBLE-buffered + depth-1 counted vmcnt (32 KB LDS) ====
// Max block-concurrency (4-5 blocks/CU) + counted overlap: wait only for tile kt,
// tile kt+1's 4 loads stay in flight across the barrier.
// MODE 0: fused QKV  C[4096,3072]: nb<16 Q (scaled by 1/sqrt(128)*log2e), nb<20 K, else V^T
// MODE 1: O-proj     C[4096,2048] fp32
template <int MODE>
__global__ __launch_bounds__(256) void gemm128(const unsigned short* __restrict__ A,
                                               const unsigned short* __restrict__ Bt,
                                               const float* __restrict__ b0,
                                               const float* __restrict__ b1,
                                               const float* __restrict__ b2,
                                               void* __restrict__ o0,
                                               void* __restrict__ o1,
                                               void* __restrict__ o2) {
    __shared__ __align__(16) unsigned short Asm[2][128 * 32];   // 8 KB per buf
    __shared__ __align__(16) unsigned short Bsm[2][128 * 32];
    const int NK = HID / 32;                     // 64 K-steps
    const int m0 = blockIdx.x * 128;
    const int nb = blockIdx.y;
    const int n0 = nb * 128;
    const int t = threadIdx.x;
    const int lane = t & 63, w = t >> 6;
    const int wr = (w >> 1) * 64, wc = (w & 1) * 64;
    const int l16 = lane & 15, lg = lane >> 4;

    f32x4 acc[4][4] = {};

    // stage tile kt (A+B, 8 KB each) into buf: 2+2 gloads/thread (4 vm-instr)
    auto stage = [&](int buf, int kt) {
        const int k0 = kt * 32;
        #pragma unroll
        for (int j = 0; j < 2; j++) {
            int c = j * 256 + t;                 // chunk 0..511 (row*4 + slot)
            int row = c >> 2, s = c & 3;
            int cg = s ^ ((row >> 1) & 3);       // pre-swizzled source col-group
            char* dA = (char*)&Asm[buf][0] + (j * 256 + w * 64) * 16;
            char* dB = (char*)&Bsm[buf][0] + (j * 256 + w * 64) * 16;
            gload16(&A[(size_t)(m0 + row) * HID + k0 + cg * 8], dA);
            gload16(&Bt[(size_t)(n0 + row) * HID + k0 + cg * 8], dB);
        }
    };

    stage(0, 0);
    int buf = 0;
    for (int kt = 0; kt < NK; kt++) {
        if (kt + 1 < NK) { stage(buf ^ 1, kt + 1); VMCNT(4); }
        else             { VMCNT(0); }
        BARRIER();
        const char* Ab = (const char*)&Asm[buf][0];
        const char* Bb = (const char*)&Bsm[buf][0];
        bf16x8 af[4], bfr[4];
        #pragma unroll
        for (int m = 0; m < 4; m++) {
            int row = wr + m * 16 + l16;
            af[m] = *(const bf16x8*)(Ab + row * 64 + ((lg ^ ((row >> 1) & 3)) << 4));
        }
        #pragma unroll
        for (int n = 0; n < 4; n++) {
            int row = wc + n * 16 + l16;
            bfr[n] = *(const bf16x8*)(Bb + row * 64 + ((lg ^ ((row >> 1) & 3)) << 4));
        }
        #pragma unroll
        for (int m = 0; m < 4; m++)
            #pragma unroll
            for (int n = 0; n < 4; n++)
                acc[m][n] = __builtin_amdgcn_mfma_f32_16x16x32_bf16(af[m], bfr[n], acc[m][n], 0, 0, 0);
        BARRIER();                               // reads retired before buf reuse
        buf ^= 1;
    }

    // epilogue
    const float sc = 0.12751744954313278f;   // 1/sqrt(128) * log2(e) — attn uses exp2
    #pragma unroll
    for (int m = 0; m < 4; m++) {
        int row = m0 + wr + m * 16 + lg * 4;
        #pragma unroll
        for (int n = 0; n < 4; n++) {
            int col = n0 + wc + n * 16 + l16;
            #pragma unroll
            for (int r = 0; r < 4; r++) {
                float v = acc[m][n][r];
                int rr = row + r;
                if constexpr (MODE == 0) {
                    if (nb < 16) {
                        v = (v + b0[col]) * sc;
                        ((unsigned short*)o0)[(size_t)rr * HID + col] = f2bf(v);
                    } else if (nb < 20) {
                        int c = col - 2048;
                        v += b1[c];
                        ((unsigned short*)o1)[(size_t)rr * KVD + c] = f2bf(v);
                    } else {
                        int c = col - 2560;
                        v += b2[c];
                        int b = rr >> 11, s = rr & (SEQ - 1);
                        ((unsigned short*)o2)[((size_t)b * KVD + c) * SEQ + s] = f2bf(v);
                    }
                } else {
                    v += b0[col];
                    ((float*)o0)[(size_t)rr * HID + col] = v;
                }
            }
        }
    }
}

// ---------------- causal GQA flash attention (r12-best: dbuf + exp2 + tree-max) ----------------
__global__ __launch_bounds__(256, 2) void attn(const unsigned short* __restrict__ Q,
                                               const unsigned short* __restrict__ K,
                                               const unsigned short* __restrict__ Vt,
                                               unsigned short* __restrict__ ctx) {
    __shared__ unsigned short Ksm[2][64 * 128];
    __shared__ unsigned short Vsm[2][128 * 64];
    const int n = blockIdx.x;                     // 0..511
    const int qt = 15 - (n >> 5);                 // LPT: heaviest q-tiles first
    const int bh = n & 31;
    const int b = bh >> 4, h = bh & 15, hk = h >> 2;
    const int t = threadIdx.x, w = t >> 6, lane = t & 63;
    const int lam = lane & 31, hi = lane >> 5;
    const int qw = qt * 128 + w * 32;
    const int qg = qw + lam;
    const size_t qrowbase = (size_t)b * SEQ + qw;

    const unsigned short* Kg = K + (size_t)b * SEQ * KVD + hk * HD;
    const unsigned short* Vg = Vt + ((size_t)b * KVD + hk * HD) * SEQ;

    bf16x8 qf[8];
    #pragma unroll
    for (int kc = 0; kc < 8; kc++)
        qf[kc] = *(const bf16x8*)&Q[(qrowbase + lam) * HID + h * HD + kc * 16 + hi * 8];

    f32x16 oacc[4] = {};
    float m = -1e30f, l = 0.f;

    auto stage = [&](int buf, int kt) {
        const int kvb = kt * 64;
        #pragma unroll
        for (int it = 0; it < 4; it++) {
            int base = it * 256 + w * 64;
            int qc = base + lane;
            {   // K tile: 64 rows x 16 slots of 16B
                int row = qc >> 4, c = qc & 15;
                gload16(&Kg[(size_t)(kvb + row) * KVD + ((c ^ (row & 7)) << 3)],
                        (char*)&Ksm[buf][0] + base * 16);
            }
            {   // V^T tile: 128 rows x 8 slots
                int row = qc >> 3, c = qc & 7;
                gload16(&Vg[(size_t)row * SEQ + kvb + ((c ^ (row & 7)) << 3)],
                        (char*)&Vsm[buf][0] + base * 16);
            }
        }
    };

    const int ntile = 2 * qt + 2;
    stage(0, 0);
    __syncthreads();
    int buf = 0;
    for (int kt = 0; kt < ntile; kt++) {
        const int kvb = kt * 64;
        if (kt + 1 < ntile) stage(buf ^ 1, kt + 1);
        if (kvb <= qw + 31) {
            const char* Kb = (const char*)&Ksm[buf][0];
            const char* Vb = (const char*)&Vsm[buf][0];
            f32x16 st0 = {}, st1 = {};
            #pragma unroll
            for (int kc = 0; kc < 8; kc++) {
                int coff = (kc * 32 + hi * 16) ^ ((lam & 7) << 4);
                bf16x8 kf0 = *(const bf16x8*)(Kb + lam * 256 + coff);
                bf16x8 kf1 = *(const bf16x8*)(Kb + (32 + lam) * 256 + coff);
                st0 = __builtin_amdgcn_mfma_f32_32x32x16_bf16(kf0, qf[kc], st0, 0, 0, 0);
                st1 = __builtin_amdgcn_mfma_f32_32x32x16_bf16(kf1, qf[kc], st1, 0, 0, 0);
            }
            if (kvb + 63 > qw) {
                #pragma unroll
                for (int r = 0; r < 16; r++) {
                    int krow = (r & 3) + 8 * (r >> 2) + 4 * hi;
                    if (kvb + krow > qg) st0[r] = -1e30f;
                    if (kvb + 32 + krow > qg) st1[r] = -1e30f;
                }
            }
            // tree max
            float mx[8];
            #pragma unroll
            for (int r = 0; r < 8; r++) mx[r] = fmaxf(st0[r], st0[r + 8]);
            #pragma unroll
            for (int r = 0; r < 8; r++) mx[r] = fmaxf(mx[r], fmaxf(st1[r], st1[r + 8]));
            #pragma unroll
            for (int r = 0; r < 4; r++) mx[r] = fmaxf(mx[r], mx[r + 4]);
            float tmax = fmaxf(fmaxf(mx[0], mx[1]), fmaxf(mx[2], mx[3]));
            tmax = fmaxf(tmax, __shfl_xor(tmax, 32));
            float mn = fmaxf(m, tmax);
            float sf = __builtin_amdgcn_exp2f(m - mn);
            m = mn;
            float rs = 0.f;
            #pragma unroll
            for (int r = 0; r < 16; r++) { st0[r] = __builtin_amdgcn_exp2f(st0[r] - mn); rs += st0[r]; }
            #pragma unroll
            for (int r = 0; r < 16; r++) { st1[r] = __builtin_amdgcn_exp2f(st1[r] - mn); rs += st1[r]; }
            rs += __shfl_xor(rs, 32);
            l = l * sf + rs;
            #pragma unroll
            for (int dc = 0; dc < 4; dc++)
                #pragma unroll
                for (int r = 0; r < 16; r++) oacc[dc][r] *= sf;
            u32 pw0[4][2], pw1[4][2];
            #pragma unroll
            for (int g = 0; g < 4; g++) {
                pw0[g][0] = cvtpk(st0[4 * g], st0[4 * g + 1]);
                pw0[g][1] = cvtpk(st0[4 * g + 2], st0[4 * g + 3]);
                pw1[g][0] = cvtpk(st1[4 * g], st1[4 * g + 1]);
                pw1[g][1] = cvtpk(st1[4 * g + 2], st1[4 * g + 3]);
            }
            #pragma unroll
            for (int kc = 0; kc < 4; kc++) {
                const u32 (*pw)[2] = (kc >> 1) ? pw1 : pw0;
                int g0 = (kc & 1) * 2;
                u32 own0 = hi ? pw[g0 + 1][0] : pw[g0][0];
                u32 own1 = hi ? pw[g0 + 1][1] : pw[g0][1];
                u32 off0 = hi ? pw[g0][0] : pw[g0 + 1][0];
                u32 off1 = hi ? pw[g0][1] : pw[g0 + 1][1];
                u32 xw0 = __shfl_xor(off0, 32);
                u32 xw1 = __shfl_xor(off1, 32);
                int4 paw;
                paw.x = hi ? xw0 : own0;
                paw.y = hi ? xw1 : own1;
                paw.z = hi ? own0 : xw0;
                paw.w = hi ? own1 : xw1;
                bf16x8 pa = __builtin_bit_cast(bf16x8, paw);
                #pragma unroll
                for (int dc = 0; dc < 4; dc++) {
                    bf16x8 vf = *(const bf16x8*)(Vb + (dc * 32 + lam) * 128 +
                                                 ((kc * 32 + hi * 16) ^ ((lam & 7) << 4)));
                    oacc[dc] = __builtin_amdgcn_mfma_f32_32x32x16_bf16(vf, pa, oacc[dc], 0, 0, 0);
                }
            }
        }
        __syncthreads();
        buf ^= 1;
    }

    float inv = 1.f / l;
    char* osm = (char*)&Ksm[0][0] + w * 8192;
    #pragma unroll
    for (int dc = 0; dc < 4; dc++)
        #pragma unroll
        for (int r = 0; r < 16; r += 2) {
            int d = dc * 32 + (r & 3) + 8 * (r >> 2) + 4 * hi;
            u32 wd = cvtpk(oacc[dc][r] * inv, oacc[dc][r + 1] * inv);
            *(u32*)(osm + lam * 256 + ((d * 2) ^ ((lam & 7) << 4))) = wd;
        }
    __syncthreads();
    const int q2 = lane >> 1, half = lane & 1;
    #pragma unroll
    for (int cc = 0; cc < 8; cc++) {
        bf16x8 v = *(const bf16x8*)(osm + q2 * 256 + (((half * 8 + cc) * 16) ^ ((q2 & 7) << 4)));
        *(bf16x8*)&ctx[(qrowbase + q2) * HID + h * HD + half * 64 + cc * 8] = v;
    }
}

extern "C" void kernel_launch(void* const* d_in, const int* in_sizes, int n_in,
                              void* d_out, int out_size, void* d_ws, size_t ws_size,
                              hipStream_t stream) {
    const float* X  = (const float*)d_in[0];
    const float* Wq = (const float*)d_in[1];
    const float* bq = (const float*)d_in[2];
    const float* Wk = (const float*)d_in[3];
    const float* bk = (const float*)d_in[4];
    const float* Wv = (const float*)d_in[5];
    const float* bv = (const float*)d_in[6];
    const float* Wo = (const float*)d_in[7];
    const float* bo = (const float*)d_in[8];
    float* out = (float*)d_out;

    const size_t MB = 1u << 20;
    char* ws = (char*)d_ws;
    if (ws_size < 76 * MB) return;
    unsigned short* Xb    = (unsigned short*)(ws + 0 * MB);    // [4096][2048] bf16
    unsigned short* Wqkvt = (unsigned short*)(ws + 16 * MB);   // [3072][2048]
    unsigned short* Wot   = (unsigned short*)(ws + 28 * MB);   // [2048][2048]
    unsigned short* Qb    = (unsigned short*)(ws + 36 * MB);   // [4096][2048]
    unsigned short* Kb    = (unsigned short*)(ws + 52 * MB);   // [4096][512]
    unsigned short* Vtb   = (unsigned short*)(ws + 56 * MB);   // [2][512][2048]
    unsigned short* Ctx   = (unsigned short*)(ws + 60 * MB);   // [4096][2048]

    cvt_f32_bf16<<<2048, 256, 0, stream>>>(X, Xb, NTOK * HID / 4);
    transpose_all<<<dim3(32, 80), 256, 0, stream>>>(Wq, Wk, Wv, Wo, Wqkvt, Wot);

    gemm128<0><<<dim3(32, 24), 256, 0, stream>>>(Xb, Wqkvt, bq, bk, bv, Qb, Kb, Vtb);

    attn<<<dim3(512), 256, 0, stream>>>(Qb, Kb, Vtb, Ctx);

    gemm128<1><<<dim3(32, 16), 256, 0, stream>>>(Ctx, Wot, bo, nullptr, nullptr, (void*)out, nullptr, nullptr);
}

// Round 18
// 203.256 us; speedup vs baseline: 1.0905x; 1.0158x over previous
//
#include <hip/hip_runtime.h>
#include <hip/hip_bf16.h>
#include <stdint.h>

#define SEQ 2048
#define BATCH 2
#define NTOK (SEQ * BATCH)   // 4096
#define HID 2048
#define NQH 16
#define NKVH 4
#define HD 128
#define KVD 512              // NKVH * HD

typedef __bf16 bf16x8 __attribute__((ext_vector_type(8)));
typedef float f32x4 __attribute__((ext_vector_type(4)));
typedef float f32x16 __attribute__((ext_vector_type(16)));
typedef unsigned int u32;

__device__ __forceinline__ unsigned short f2bf(float f) {
    uint32_t u = __builtin_bit_cast(uint32_t, f);
    uint32_t r = (u + 0x7fffu + ((u >> 16) & 1u)) >> 16;
    return (unsigned short)r;
}

__device__ __forceinline__ u32 cvtpk(float lo, float hi) {
    u32 r;
    asm("v_cvt_pk_bf16_f32 %0, %1, %2" : "=v"(r) : "v"(lo), "v"(hi));
    return r;
}

// async global->LDS, 16B per lane. lds ptr must be wave-uniform (HW appends lane*16).
__device__ __forceinline__ void gload16(const void* g, void* l) {
    __builtin_amdgcn_global_load_lds((const __attribute__((address_space(1))) u32*)g,
                                     (__attribute__((address_space(3))) u32*)l, 16, 0, 0);
}

#define BARRIER()  asm volatile("s_barrier" ::: "memory")
#define VMCNT(n)   asm volatile("s_waitcnt vmcnt(" #n ")" ::: "memory")

// ---------------- fp32 -> bf16 convert (vectorized) ----------------
__global__ void cvt_f32_bf16(const float* __restrict__ in, unsigned short* __restrict__ out, int n4) {
    int i = blockIdx.x * blockDim.x + threadIdx.x;
    int stride = gridDim.x * blockDim.x;
    for (; i < n4; i += stride) {
        float4 v = ((const float4*)in)[i];
        ushort4 o;
        o.x = f2bf(v.x); o.y = f2bf(v.y); o.z = f2bf(v.z); o.w = f2bf(v.w);
        ((ushort4*)out)[i] = o;
    }
}

// ------------- all W [2048][N] fp32 -> Wt [N][2048] bf16, one launch --------------
__global__ __launch_bounds__(256) void transpose_all(const float* __restrict__ Wq,
                                                     const float* __restrict__ Wk,
                                                     const float* __restrict__ Wv,
                                                     const float* __restrict__ Wo,
                                                     unsigned short* __restrict__ Wqkvt,
                                                     unsigned short* __restrict__ Wot) {
    __shared__ unsigned short tile[64][72];
    const int y = blockIdx.y;
    const float* W;
    unsigned short* dst;
    int N, ny;
    if (y < 32)      { W = Wq; dst = Wqkvt;                        N = 2048; ny = y; }
    else if (y < 40) { W = Wk; dst = Wqkvt + (size_t)2048 * HID;   N = 512;  ny = y - 32; }
    else if (y < 48) { W = Wv; dst = Wqkvt + (size_t)2560 * HID;   N = 512;  ny = y - 40; }
    else             { W = Wo; dst = Wot;                          N = 2048; ny = y - 48; }
    const int k0 = blockIdx.x * 64, n0 = ny * 64;
    const int t = threadIdx.x;
    const int r = t >> 4;          // 0..15
    const int c4 = (t & 15) * 4;   // 0..60
    #pragma unroll
    for (int i = 0; i < 4; i++) {
        int row = r + i * 16;
        float4 v = *(const float4*)&W[(size_t)(k0 + row) * N + n0 + c4];
        tile[row][c4 + 0] = f2bf(v.x);
        tile[row][c4 + 1] = f2bf(v.y);
        tile[row][c4 + 2] = f2bf(v.z);
        tile[row][c4 + 3] = f2bf(v.w);
    }
    __syncthreads();
    #pragma unroll
    for (int i = 0; i < 4; i++) {
        int nrow = r + i * 16;
        ushort4 o;
        o.x = tile[c4 + 0][nrow];
        o.y = tile[c4 + 1][nrow];
        o.z = tile[c4 + 2][nrow];
        o.w = tile[c4 + 3][nrow];
        *(ushort4*)&dst[(size_t)(n0 + nrow) * HID + k0 + c4] = o;
    }
}

// ==== 128^2-tile, BK=32, TRIPLE-buffered + counted vmcnt (48 KB LDS, r12-proven) ====
// MODE 0: fused QKV  C[4096,3072]: nb<16 Q (scaled by 1/sqrt(128)*log2e), nb<20 K, else V^T
// MODE 1: O-proj     C[4096,2048] fp32
template <int MODE>
__global__ __launch_bounds__(256) void gemm128(const unsigned short* __restrict__ A,
                                               const unsigned short* __restrict__ Bt,
                                               const float* __restrict__ b0,
                                               const float* __restrict__ b1,
                                               const float* __restrict__ b2,
                                               void* __restrict__ o0,
                                               void* __restrict__ o1,
                                               void* __restrict__ o2) {
    __shared__ __align__(16) unsigned short Asm[3][128 * 32];   // 8 KB per buf
    __shared__ __align__(16) unsigned short Bsm[3][128 * 32];
    const int NK = HID / 32;                     // 64 K-steps
    const int m0 = blockIdx.x * 128;
    const int nb = blockIdx.y;
    const int n0 = nb * 128;
    const int t = threadIdx.x;
    const int lane = t & 63, w = t >> 6;
    const int wr = (w >> 1) * 64, wc = (w & 1) * 64;
    const int l16 = lane & 15, lg = lane >> 4;

    f32x4 acc[4][4] = {};

    // stage tile kt (A+B, 8 KB each) into buf: 4 vm-instr per wave
    auto stage = [&](int buf, int kt) {
        const int k0 = kt * 32;
        #pragma unroll
        for (int j = 0; j < 2; j++) {
            int c = j * 256 + t;                 // chunk 0..511 (row*4 + slot)
            int row = c >> 2, s = c & 3;
            int cg = s ^ ((row >> 1) & 3);       // pre-swizzled source col-group
            char* dA = (char*)&Asm[buf][0] + (j * 256 + w * 64) * 16;
            char* dB = (char*)&Bsm[buf][0] + (j * 256 + w * 64) * 16;
            gload16(&A[(size_t)(m0 + row) * HID + k0 + cg * 8], dA);
            gload16(&Bt[(size_t)(n0 + row) * HID + k0 + cg * 8], dB);
        }
    };

    stage(0, 0);
    stage(1, 1);
    for (int kt = 0; kt < NK; kt++) {
        if (kt + 2 < NK) stage((kt + 2) % 3, kt + 2);
        // wait for tile kt only (4 vm-instr per in-flight tile)
        if (kt < NK - 2)       { VMCNT(8); }
        else if (kt == NK - 2) { VMCNT(4); }
        else                   { VMCNT(0); }
        BARRIER();
        const char* Ab = (const char*)&Asm[kt % 3][0];
        const char* Bb = (const char*)&Bsm[kt % 3][0];
        bf16x8 af[4], bfr[4];
        #pragma unroll
        for (int m = 0; m < 4; m++) {
            int row = wr + m * 16 + l16;
            af[m] = *(const bf16x8*)(Ab + row * 64 + ((lg ^ ((row >> 1) & 3)) << 4));
        }
        #pragma unroll
        for (int n = 0; n < 4; n++) {
            int row = wc + n * 16 + l16;
            bfr[n] = *(const bf16x8*)(Bb + row * 64 + ((lg ^ ((row >> 1) & 3)) << 4));
        }
        #pragma unroll
        for (int m = 0; m < 4; m++)
            #pragma unroll
            for (int n = 0; n < 4; n++)
                acc[m][n] = __builtin_amdgcn_mfma_f32_16x16x32_bf16(af[m], bfr[n], acc[m][n], 0, 0, 0);
        BARRIER();                               // reads retired before buf reuse
    }

    // epilogue
    const float sc = 0.12751744954313278f;   // 1/sqrt(128) * log2(e) — attn uses exp2
    #pragma unroll
    for (int m = 0; m < 4; m++) {
        int row = m0 + wr + m * 16 + lg * 4;
        #pragma unroll
        for (int n = 0; n < 4; n++) {
            int col = n0 + wc + n * 16 + l16;
            #pragma unroll
            for (int r = 0; r < 4; r++) {
                float v = acc[m][n][r];
                int rr = row + r;
                if constexpr (MODE == 0) {
                    if (nb < 16) {
                        v = (v + b0[col]) * sc;
                        ((unsigned short*)o0)[(size_t)rr * HID + col] = f2bf(v);
                    } else if (nb < 20) {
                        int c = col - 2048;
                        v += b1[c];
                        ((unsigned short*)o1)[(size_t)rr * KVD + c] = f2bf(v);
                    } else {
                        int c = col - 2560;
                        v += b2[c];
                        int b = rr >> 11, s = rr & (SEQ - 1);
                        ((unsigned short*)o2)[((size_t)b * KVD + c) * SEQ + s] = f2bf(v);
                    }
                } else {
                    v += b0[col];
                    ((float*)o0)[(size_t)rr * HID + col] = v;
                }
            }
        }
    }
}

// ---------------- causal GQA flash attention (r12-best + 4-bit K swizzle) ----------------
__global__ __launch_bounds__(256, 2) void attn(const unsigned short* __restrict__ Q,
                                               const unsigned short* __restrict__ K,
                                               const unsigned short* __restrict__ Vt,
                                               unsigned short* __restrict__ ctx) {
    __shared__ unsigned short Ksm[2][64 * 128];
    __shared__ unsigned short Vsm[2][128 * 64];
    const int n = blockIdx.x;                     // 0..511
    const int qt = 15 - (n >> 5);                 // LPT: heaviest q-tiles first
    const int bh = n & 31;
    const int b = bh >> 4, h = bh & 15, hk = h >> 2;
    const int t = threadIdx.x, w = t >> 6, lane = t & 63;
    const int lam = lane & 31, hi = lane >> 5;
    const int qw = qt * 128 + w * 32;
    const int qg = qw + lam;
    const size_t qrowbase = (size_t)b * SEQ + qw;

    const unsigned short* Kg = K + (size_t)b * SEQ * KVD + hk * HD;
    const unsigned short* Vg = Vt + ((size_t)b * KVD + hk * HD) * SEQ;

    bf16x8 qf[8];
    #pragma unroll
    for (int kc = 0; kc < 8; kc++)
        qf[kc] = *(const bf16x8*)&Q[(qrowbase + lam) * HID + h * HD + kc * 16 + hi * 8];

    f32x16 oacc[4] = {};
    float m = -1e30f, l = 0.f;

    auto stage = [&](int buf, int kt) {
        const int kvb = kt * 64;
        #pragma unroll
        for (int it = 0; it < 4; it++) {
            int base = it * 256 + w * 64;
            int qc = base + lane;
            {   // K tile: 64 rows x 16 slots of 16B, 4-bit XOR swizzle (2-way banks)
                int row = qc >> 4, c = qc & 15;
                gload16(&Kg[(size_t)(kvb + row) * KVD + ((c ^ (row & 15)) << 3)],
                        (char*)&Ksm[buf][0] + base * 16);
            }
            {   // V^T tile: 128 rows x 8 slots (3-bit XOR — max spread for 8 slots)
                int row = qc >> 3, c = qc & 7;
                gload16(&Vg[(size_t)row * SEQ + kvb + ((c ^ (row & 7)) << 3)],
                        (char*)&Vsm[buf][0] + base * 16);
            }
        }
    };

    const int ntile = 2 * qt + 2;
    stage(0, 0);
    __syncthreads();
    int buf = 0;
    for (int kt = 0; kt < ntile; kt++) {
        const int kvb = kt * 64;
        if (kt + 1 < ntile) stage(buf ^ 1, kt + 1);
        if (kvb <= qw + 31) {
            const char* Kb = (const char*)&Ksm[buf][0];
            const char* Vb = (const char*)&Vsm[buf][0];
            f32x16 st0 = {}, st1 = {};
            #pragma unroll
            for (int kc = 0; kc < 8; kc++) {
                int coff = (kc * 32 + hi * 16) ^ ((lam & 15) << 4);
                bf16x8 kf0 = *(const bf16x8*)(Kb + lam * 256 + coff);
                bf16x8 kf1 = *(const bf16x8*)(Kb + (32 + lam) * 256 + coff);
                st0 = __builtin_amdgcn_mfma_f32_32x32x16_bf16(kf0, qf[kc], st0, 0, 0, 0);
                st1 = __builtin_amdgcn_mfma_f32_32x32x16_bf16(kf1, qf[kc], st1, 0, 0, 0);
            }
            if (kvb + 63 > qw) {
                #pragma unroll
                for (int r = 0; r < 16; r++) {
                    int krow = (r & 3) + 8 * (r >> 2) + 4 * hi;
                    if (kvb + krow > qg) st0[r] = -1e30f;
                    if (kvb + 32 + krow > qg) st1[r] = -1e30f;
                }
            }
            // tree max
            float mx[8];
            #pragma unroll
            for (int r = 0; r < 8; r++) mx[r] = fmaxf(st0[r], st0[r + 8]);
            #pragma unroll
            for (int r = 0; r < 8; r++) mx[r] = fmaxf(mx[r], fmaxf(st1[r], st1[r + 8]));
            #pragma unroll
            for (int r = 0; r < 4; r++) mx[r] = fmaxf(mx[r], mx[r + 4]);
            float tmax = fmaxf(fmaxf(mx[0], mx[1]), fmaxf(mx[2], mx[3]));
            tmax = fmaxf(tmax, __shfl_xor(tmax, 32));
            float mn = fmaxf(m, tmax);
            float sf = __builtin_amdgcn_exp2f(m - mn);
            m = mn;
            float rs = 0.f;
            #pragma unroll
            for (int r = 0; r < 16; r++) { st0[r] = __builtin_amdgcn_exp2f(st0[r] - mn); rs += st0[r]; }
            #pragma unroll
            for (int r = 0; r < 16; r++) { st1[r] = __builtin_amdgcn_exp2f(st1[r] - mn); rs += st1[r]; }
            rs += __shfl_xor(rs, 32);
            l = l * sf + rs;
            #pragma unroll
            for (int dc = 0; dc < 4; dc++)
                #pragma unroll
                for (int r = 0; r < 16; r++) oacc[dc][r] *= sf;
            u32 pw0[4][2], pw1[4][2];
            #pragma unroll
            for (int g = 0; g < 4; g++) {
                pw0[g][0] = cvtpk(st0[4 * g], st0[4 * g + 1]);
                pw0[g][1] = cvtpk(st0[4 * g + 2], st0[4 * g + 3]);
                pw1[g][0] = cvtpk(st1[4 * g], st1[4 * g + 1]);
                pw1[g][1] = cvtpk(st1[4 * g + 2], st1[4 * g + 3]);
            }
            #pragma unroll
            for (int kc = 0; kc < 4; kc++) {
                const u32 (*pw)[2] = (kc >> 1) ? pw1 : pw0;
                int g0 = (kc & 1) * 2;
                u32 own0 = hi ? pw[g0 + 1][0] : pw[g0][0];
                u32 own1 = hi ? pw[g0 + 1][1] : pw[g0][1];
                u32 off0 = hi ? pw[g0][0] : pw[g0 + 1][0];
                u32 off1 = hi ? pw[g0][1] : pw[g0 + 1][1];
                u32 xw0 = __shfl_xor(off0, 32);
                u32 xw1 = __shfl_xor(off1, 32);
                int4 paw;
                paw.x = hi ? xw0 : own0;
                paw.y = hi ? xw1 : own1;
                paw.z = hi ? own0 : xw0;
                paw.w = hi ? own1 : xw1;
                bf16x8 pa = __builtin_bit_cast(bf16x8, paw);
                #pragma unroll
                for (int dc = 0; dc < 4; dc++) {
                    bf16x8 vf = *(const bf16x8*)(Vb + (dc * 32 + lam) * 128 +
                                                 ((kc * 32 + hi * 16) ^ ((lam & 7) << 4)));
                    oacc[dc] = __builtin_amdgcn_mfma_f32_32x32x16_bf16(vf, pa, oacc[dc], 0, 0, 0);
                }
            }
        }
        __syncthreads();
        buf ^= 1;
    }

    float inv = 1.f / l;
    char* osm = (char*)&Ksm[0][0] + w * 8192;
    #pragma unroll
    for (int dc = 0; dc < 4; dc++)
        #pragma unroll
        for (int r = 0; r < 16; r += 2) {
            int d = dc * 32 + (r & 3) + 8 * (r >> 2) + 4 * hi;
            u32 wd = cvtpk(oacc[dc][r] * inv, oacc[dc][r + 1] * inv);
            *(u32*)(osm + lam * 256 + ((d * 2) ^ ((lam & 7) << 4))) = wd;
        }
    __syncthreads();
    const int q2 = lane >> 1, half = lane & 1;
    #pragma unroll
    for (int cc = 0; cc < 8; cc++) {
        bf16x8 v = *(const bf16x8*)(osm + q2 * 256 + (((half * 8 + cc) * 16) ^ ((q2 & 7) << 4)));
        *(bf16x8*)&ctx[(qrowbase + q2) * HID + h * HD + half * 64 + cc * 8] = v;
    }
}

extern "C" void kernel_launch(void* const* d_in, const int* in_sizes, int n_in,
                              void* d_out, int out_size, void* d_ws, size_t ws_size,
                              hipStream_t stream) {
    const float* X  = (const float*)d_in[0];
    const float* Wq = (const float*)d_in[1];
    const float* bq = (const float*)d_in[2];
    const float* Wk = (const float*)d_in[3];
    const float* bk = (const float*)d_in[4];
    const float* Wv = (const float*)d_in[5];
    const float* bv = (const float*)d_in[6];
    const float* Wo = (const float*)d_in[7];
    const float* bo = (const float*)d_in[8];
    float* out = (float*)d_out;

    const size_t MB = 1u << 20;
    char* ws = (char*)d_ws;
    if (ws_size < 76 * MB) return;
    unsigned short* Xb    = (unsigned short*)(ws + 0 * MB);    // [4096][2048] bf16
    unsigned short* Wqkvt = (unsigned short*)(ws + 16 * MB);   // [3072][2048]
    unsigned short* Wot   = (unsigned short*)(ws + 28 * MB);   // [2048][2048]
    unsigned short* Qb    = (unsigned short*)(ws + 36 * MB);   // [4096][2048]
    unsigned short* Kb    = (unsigned short*)(ws + 52 * MB);   // [4096][512]
    unsigned short* Vtb   = (unsigned short*)(ws + 56 * MB);   // [2][512][2048]
    unsigned short* Ctx   = (unsigned short*)(ws + 60 * MB);   // [4096][2048]

    cvt_f32_bf16<<<2048, 256, 0, stream>>>(X, Xb, NTOK * HID / 4);
    transpose_all<<<dim3(32, 80), 256, 0, stream>>>(Wq, Wk, Wv, Wo, Wqkvt, Wot);

    gemm128<0><<<dim3(32, 24), 256, 0, stream>>>(Xb, Wqkvt, bq, bk, bv, Qb, Kb, Vtb);

    attn<<<dim3(512), 256, 0, stream>>>(Qb, Kb, Vtb, Ctx);

    gemm128<1><<<dim3(32, 16), 256, 0, stream>>>(Ctx, Wot, bo, nullptr, nullptr, (void*)out, nullptr, nullptr);
}